// Round 5
// baseline (12859.441 us; speedup 1.0000x reference)
//
#include <hip/hip_runtime.h>
#include <math.h>

// Problem constants (fixed by reference: x (9,256,32,32) fp32, att (9,32,32) fp32)
#define MR 1024      // m = 32*32 query locations
#define NC 8192      // n = 8*32*32 target locations
#define NCH 256      // channels
#define OT_ITERS 1000
#define IMG_STRIDE 262144  // 256*1024 floats per image
#define VEPS 2e-4f         // v-stationarity threshold (fp32 ulp at |v|~1e2 is ~8e-6)

__device__ inline float wredMax(float v){
#pragma unroll
  for (int m = 32; m >= 1; m >>= 1) v = fmaxf(v, __shfl_xor(v, m, 64));
  return v;
}
__device__ inline float wredMin(float v){
#pragma unroll
  for (int m = 32; m >= 1; m >>= 1) v = fminf(v, __shfl_xor(v, m, 64));
  return v;
}
__device__ inline float wredSum(float v){
#pragma unroll
  for (int m = 32; m >= 1; m >>= 1) v += __shfl_xor(v, m, 64);
  return v;
}

// monotone float<->uint key (for atomicMin/Max over floats incl. negatives)
__device__ inline unsigned fkey(float f){
  unsigned b = __float_as_uint(f);
  return (b & 0x80000000u) ? ~b : (b | 0x80000000u);
}
__device__ inline float funkey(unsigned k){
  return (k & 0x80000000u) ? __uint_as_float(k & 0x7fffffffu) : __uint_as_float(~k);
}

// K1: squared norms qq/tt, log marginals, zero-init u,v,acc, minmax keys, ctl flags
__global__ __launch_bounds__(256) void kPrep(const float* __restrict__ x,
                                             const float* __restrict__ att,
                                             float* __restrict__ qq, float* __restrict__ tt,
                                             float* __restrict__ logmu, float* __restrict__ lognu,
                                             float* __restrict__ u, float* __restrict__ v,
                                             float* __restrict__ acc, unsigned* __restrict__ prmI,
                                             int* __restrict__ ctl){
  int idx = blockIdx.x * 256 + threadIdx.x;
  if (idx < 9216){
    int img = idx >> 10, pos = idx & 1023;
    const float* p = x + img * IMG_STRIDE + pos;
    float s = 0.f;
#pragma unroll 8
    for (int c = 0; c < NCH; ++c){ float a = p[c * 1024]; s += a * a; }
    float lg = logf(att[idx]);
    if (img == 0){ qq[idx] = s;        logmu[idx] = lg; }
    else         { tt[idx - 1024] = s; lognu[idx - 1024] = lg; }
  }
  if (idx < MR) u[idx] = 0.f;
  if (idx < NC) v[idx] = 0.f;
  if (idx == 0){
    *acc = 0.f; prmI[0] = 0xFFFFFFFFu; prmI[1] = 0u;
    ctl[0] = 0;  // slot for even iters (zeroed before v-pass(0) writes it)
    ctl[1] = 1;  // slot read by u-pass(1)... must start "changed" -> actually read at it=1 is slot 0; slot 1 read at it=2. Init both harmless: [1]=1 keeps it=... safe.
  }
}

// K2: M[i][j] = qq[i] + tt[j] - 2 * Q_i . T_j ; also global min/max via key atomics
__global__ __launch_bounds__(256) void kGemmM(const float* __restrict__ x,
                                              const float* __restrict__ qq,
                                              const float* __restrict__ tt,
                                              float* __restrict__ M,
                                              unsigned* __restrict__ prmI){
  __shared__ float As[16][68];
  __shared__ float Bs[16][68];
  __shared__ float smn[4], smx[4];
  int jb = blockIdx.x;              // 0..127 (column tiles of 64; never straddle image)
  int ib = blockIdx.y;              // 0..15
  int i0 = ib * 64;
  int j0 = jb * 64;
  int k  = j0 >> 10, p0 = j0 & 1023;
  const float* A = x + i0;
  const float* B = x + (1 + k) * IMG_STRIDE + p0;
  int tid = threadIdx.x;
  int lr = tid >> 4, lc = (tid & 15) * 4;
  int ty = tid >> 4, tx = tid & 15;
  float accv[4][4] = {};
  for (int kt = 0; kt < 16; ++kt){
    int c = kt * 16 + lr;
    float4 av = *(const float4*)(A + c * 1024 + lc);
    float4 bv = *(const float4*)(B + c * 1024 + lc);
    *(float4*)(&As[lr][lc]) = av;
    *(float4*)(&Bs[lr][lc]) = bv;
    __syncthreads();
#pragma unroll
    for (int kk = 0; kk < 16; ++kk){
      float4 a = *(const float4*)(&As[kk][ty * 4]);
      float4 b = *(const float4*)(&Bs[kk][tx * 4]);
      float ar[4] = {a.x, a.y, a.z, a.w};
      float br[4] = {b.x, b.y, b.z, b.w};
#pragma unroll
      for (int r = 0; r < 4; ++r)
#pragma unroll
        for (int cc = 0; cc < 4; ++cc) accv[r][cc] += ar[r] * br[cc];
    }
    __syncthreads();
  }
  float tmn = INFINITY, tmx = -INFINITY;
#pragma unroll
  for (int r = 0; r < 4; ++r){
    int i = i0 + ty * 4 + r;
    float qi = qq[i];
    float o[4];
#pragma unroll
    for (int cc = 0; cc < 4; ++cc){
      o[cc] = qi + tt[j0 + tx * 4 + cc] - 2.f * accv[r][cc];
      tmn = fminf(tmn, o[cc]); tmx = fmaxf(tmx, o[cc]);
    }
    float4 ov = { o[0], o[1], o[2], o[3] };
    *(float4*)(M + (long)i * NC + j0 + tx * 4) = ov;
  }
  int lane = tid & 63, w = tid >> 6;
  tmn = wredMin(tmn); tmx = wredMax(tmx);
  if (lane == 0){ smn[w] = tmn; smx[w] = tmx; }
  __syncthreads();
  if (tid == 0){
    float bmn = fminf(fminf(smn[0], smn[1]), fminf(smn[2], smn[3]));
    float bmx = fmaxf(fmaxf(smx[0], smx[1]), fmaxf(smx[2], smx[3]));
    atomicMin(&prmI[0], fkey(bmn));
    atomicMax(&prmI[1], fkey(bmx));
  }
}

// K2b: one pass over M -> Mq (uint16 row-major) + Mtq (uint16 transposed); writes prm scale
__global__ __launch_bounds__(256) void kQuantTrans(const float* __restrict__ M,
                                                   unsigned short* __restrict__ Mq,
                                                   unsigned short* __restrict__ Mtq,
                                                   float* __restrict__ prm){
  __shared__ float tile[64][65];
  const unsigned* prmI = (const unsigned*)prm;
  float mn = funkey(prmI[0]);
  float mx = funkey(prmI[1]);
  float rng = mx - mn;
  float inv = (rng > 0.f) ? 65535.0f / rng : 0.f;
  float sc  = (rng > 0.f) ? rng / 65535.0f : 0.f;
  int i0 = blockIdx.y * 64;
  int j0 = blockIdx.x * 64;
  int t = threadIdx.x;
  int tc = t & 63, tr = t >> 6;
#pragma unroll
  for (int rr = 0; rr < 64; rr += 4)
    tile[rr + tr][tc] = M[(long)(i0 + rr + tr) * NC + j0 + tc];
  __syncthreads();
#pragma unroll
  for (int rr = 0; rr < 64; rr += 4){
    float a = tile[rr + tr][tc];
    int qa = (int)lrintf((a - mn) * inv);
    qa = qa < 0 ? 0 : (qa > 65535 ? 65535 : qa);
    Mq[(long)(i0 + rr + tr) * NC + j0 + tc] = (unsigned short)qa;
    float b = tile[tc][rr + tr];
    int qb = (int)lrintf((b - mn) * inv);
    qb = qb < 0 ? 0 : (qb > 65535 ? 65535 : qb);
    Mtq[(long)(j0 + rr + tr) * MR + i0 + tc] = (unsigned short)qb;
  }
  if (blockIdx.x == 0 && blockIdx.y == 0 && t == 0){ prm[2] = mn; prm[3] = sc; }
}

// K3: u-pass on quantized M; 2 rows per block; early-return once v is stationary
__global__ __launch_bounds__(256) void kUPassQ(const unsigned short* __restrict__ Mq,
                                               const float* __restrict__ v,
                                               const float* __restrict__ logmu,
                                               float* __restrict__ u,
                                               const float* __restrict__ prm,
                                               const int* __restrict__ ctl, int it){
  if (it != 0 && ctl[(it - 1) & 1] == 0) return;   // converged: exact no-op
  int b = blockIdx.x, tid = threadIdx.x;
  float mn = prm[2], s = prm[3];
  int r0 = 2 * b;
  const unsigned short* R0 = Mq + (long)r0 * NC;
  const unsigned short* R1 = R0 + NC;
  float t0[32], t1[32];
  float mx0 = -INFINITY, mx1 = -INFINITY;
#pragma unroll
  for (int kb = 0; kb < 4; ++kb){
    int cidx = kb * 2048 + tid * 8;
    uint4 qa = *(const uint4*)(R0 + cidx);
    uint4 qb = *(const uint4*)(R1 + cidx);
    float4 v0 = *(const float4*)(v + cidx);
    float4 v1 = *(const float4*)(v + cidx + 4);
    float a0 = fmaf(s, (float)(qa.x & 0xFFFFu), v0.x);
    float a1 = fmaf(s, (float)(qa.x >> 16),     v0.y);
    float a2 = fmaf(s, (float)(qa.y & 0xFFFFu), v0.z);
    float a3 = fmaf(s, (float)(qa.y >> 16),     v0.w);
    float a4 = fmaf(s, (float)(qa.z & 0xFFFFu), v1.x);
    float a5 = fmaf(s, (float)(qa.z >> 16),     v1.y);
    float a6 = fmaf(s, (float)(qa.w & 0xFFFFu), v1.z);
    float a7 = fmaf(s, (float)(qa.w >> 16),     v1.w);
    float c0 = fmaf(s, (float)(qb.x & 0xFFFFu), v0.x);
    float c1 = fmaf(s, (float)(qb.x >> 16),     v0.y);
    float c2 = fmaf(s, (float)(qb.y & 0xFFFFu), v0.z);
    float c3 = fmaf(s, (float)(qb.y >> 16),     v0.w);
    float c4 = fmaf(s, (float)(qb.z & 0xFFFFu), v1.x);
    float c5 = fmaf(s, (float)(qb.z >> 16),     v1.y);
    float c6 = fmaf(s, (float)(qb.w & 0xFFFFu), v1.z);
    float c7 = fmaf(s, (float)(qb.w >> 16),     v1.w);
    t0[kb*8+0]=a0; t0[kb*8+1]=a1; t0[kb*8+2]=a2; t0[kb*8+3]=a3;
    t0[kb*8+4]=a4; t0[kb*8+5]=a5; t0[kb*8+6]=a6; t0[kb*8+7]=a7;
    t1[kb*8+0]=c0; t1[kb*8+1]=c1; t1[kb*8+2]=c2; t1[kb*8+3]=c3;
    t1[kb*8+4]=c4; t1[kb*8+5]=c5; t1[kb*8+6]=c6; t1[kb*8+7]=c7;
    mx0 = fmaxf(mx0, fmaxf(fmaxf(fmaxf(a0,a1),fmaxf(a2,a3)), fmaxf(fmaxf(a4,a5),fmaxf(a6,a7))));
    mx1 = fmaxf(mx1, fmaxf(fmaxf(fmaxf(c0,c1),fmaxf(c2,c3)), fmaxf(fmaxf(c4,c5),fmaxf(c6,c7))));
  }
  __shared__ float redA0[4], redA1[4], redB0[4], redB1[4];
  int lane = tid & 63, w = tid >> 6;
  float wm0 = wredMax(mx0), wm1 = wredMax(mx1);
  if (lane == 0){ redA0[w] = wm0; redA1[w] = wm1; }
  __syncthreads();
  float bm0 = fmaxf(fmaxf(redA0[0], redA0[1]), fmaxf(redA0[2], redA0[3]));
  float bm1 = fmaxf(fmaxf(redA1[0], redA1[1]), fmaxf(redA1[2], redA1[3]));
  float s0 = 0.f, s1 = 0.f;
#pragma unroll
  for (int q = 0; q < 32; ++q){ s0 += __expf(t0[q] - bm0); s1 += __expf(t1[q] - bm1); }
  s0 = wredSum(s0); s1 = wredSum(s1);
  if (lane == 0){ redB0[w] = s0; redB1[w] = s1; }
  __syncthreads();
  if (tid == 0){
    u[r0]     = logmu[r0]     - mn - (bm0 + __logf(redB0[0] + redB0[1] + redB0[2] + redB0[3]));
    u[r0 + 1] = logmu[r0 + 1] - mn - (bm1 + __logf(redB1[0] + redB1[1] + redB1[2] + redB1[3]));
  }
}

// K4: v-pass on quantized Mt; 16 cols per block; sets "changed" flag, early-returns too
__global__ __launch_bounds__(256) void kVPassQ(const unsigned short* __restrict__ Mtq,
                                               const float* __restrict__ u,
                                               const float* __restrict__ lognu,
                                               float* __restrict__ v,
                                               const float* __restrict__ prm,
                                               int* __restrict__ ctl, int it){
  if (it != 0 && ctl[(it - 1) & 1] == 0) return;   // converged: exact no-op
  __shared__ float ulds[1024];
  __shared__ int blkchg;
  int tid = threadIdx.x;
  if (tid == 0) blkchg = 0;
  // block 0 zeroes the NEXT iteration's flag slot (its previous readers all finished)
  if (blockIdx.x == 0 && tid == 1) ctl[(it + 1) & 1] = 0;
  float mn = prm[2], s = prm[3];
  *(float4*)(&ulds[tid * 4]) = *(const float4*)(u + tid * 4);
  __syncthreads();
  int w = tid >> 6, lane = tid & 63;
#pragma unroll
  for (int cc = 0; cc < 4; ++cc){
    int j = blockIdx.x * 16 + w * 4 + cc;
    const unsigned short* R = Mtq + (long)j * MR;
    uint4 qa = *(const uint4*)(R + lane * 8);
    uint4 qb = *(const uint4*)(R + 512 + lane * 8);
    float4 ua0 = *(const float4*)(&ulds[lane * 8]);
    float4 ua1 = *(const float4*)(&ulds[lane * 8 + 4]);
    float4 ub0 = *(const float4*)(&ulds[512 + lane * 8]);
    float4 ub1 = *(const float4*)(&ulds[512 + lane * 8 + 4]);
    float tv[16];
    tv[0]  = fmaf(s, (float)(qa.x & 0xFFFFu), ua0.x);
    tv[1]  = fmaf(s, (float)(qa.x >> 16),     ua0.y);
    tv[2]  = fmaf(s, (float)(qa.y & 0xFFFFu), ua0.z);
    tv[3]  = fmaf(s, (float)(qa.y >> 16),     ua0.w);
    tv[4]  = fmaf(s, (float)(qa.z & 0xFFFFu), ua1.x);
    tv[5]  = fmaf(s, (float)(qa.z >> 16),     ua1.y);
    tv[6]  = fmaf(s, (float)(qa.w & 0xFFFFu), ua1.z);
    tv[7]  = fmaf(s, (float)(qa.w >> 16),     ua1.w);
    tv[8]  = fmaf(s, (float)(qb.x & 0xFFFFu), ub0.x);
    tv[9]  = fmaf(s, (float)(qb.x >> 16),     ub0.y);
    tv[10] = fmaf(s, (float)(qb.y & 0xFFFFu), ub0.z);
    tv[11] = fmaf(s, (float)(qb.y >> 16),     ub0.w);
    tv[12] = fmaf(s, (float)(qb.z & 0xFFFFu), ub1.x);
    tv[13] = fmaf(s, (float)(qb.z >> 16),     ub1.y);
    tv[14] = fmaf(s, (float)(qb.w & 0xFFFFu), ub1.z);
    tv[15] = fmaf(s, (float)(qb.w >> 16),     ub1.w);
    float mx = -INFINITY;
#pragma unroll
    for (int q = 0; q < 16; ++q) mx = fmaxf(mx, tv[q]);
    mx = wredMax(mx);
    float sm = 0.f;
#pragma unroll
    for (int q = 0; q < 16; ++q) sm += __expf(tv[q] - mx);
    sm = wredSum(sm);
    if (lane == 0){
      float nv = lognu[j] - mn - (mx + __logf(sm));
      if (fabsf(nv - v[j]) > VEPS) blkchg = 1;   // LDS store, no atomic needed (any-write wins)
      v[j] = nv;
    }
  }
  __syncthreads();
  if (tid == 0 && blkchg) ctl[it & 1] = 1;   // benign same-value race across blocks
}

// K5: o = P@T rows, diff = mu*Q - o, acc += sum_i ||diff_i||_2 ; 4 rows per block
__global__ __launch_bounds__(256) void kFinal(const float* __restrict__ x,
                                              const float* __restrict__ att,
                                              const float* __restrict__ M,
                                              const float* __restrict__ u,
                                              const float* __restrict__ v,
                                              float* __restrict__ acc){
  __shared__ float pch[4][256];
  __shared__ float redS[4];
  int tid = threadIdx.x;
  int r0 = blockIdx.x * 4;
  float u4[4];
#pragma unroll
  for (int rr = 0; rr < 4; ++rr) u4[rr] = u[r0 + rr];
  float o[4] = {0.f, 0.f, 0.f, 0.f};
  for (int jc = 0; jc < NC; jc += 256){
    float vv = v[jc + tid];
#pragma unroll
    for (int rr = 0; rr < 4; ++rr)
      pch[rr][tid] = __expf(M[(long)(r0 + rr) * NC + jc + tid] + u4[rr] + vv);
    __syncthreads();
    int k = jc >> 10;
    const float* Tp = x + (1 + k) * IMG_STRIDE + tid * 1024 + (jc & 1023);
    for (int jj = 0; jj < 256; jj += 4){
      float4 tv = *(const float4*)(Tp + jj);
      float tq[4] = {tv.x, tv.y, tv.z, tv.w};
#pragma unroll
      for (int q = 0; q < 4; ++q){
        o[0] += pch[0][jj + q] * tq[q];
        o[1] += pch[1][jj + q] * tq[q];
        o[2] += pch[2][jj + q] * tq[q];
        o[3] += pch[3][jj + q] * tq[q];
      }
    }
    __syncthreads();
  }
  int lane = tid & 63, wid = tid >> 6;
  float dtot = 0.f;
#pragma unroll
  for (int rr = 0; rr < 4; ++rr){
    float mu = att[r0 + rr];
    float qv = x[tid * 1024 + (r0 + rr)];
    float diff = mu * qv - o[rr];
    float wsum = wredSum(diff * diff);
    if (lane == 0) redS[wid] = wsum;
    __syncthreads();
    if (tid == 0) dtot += sqrtf(redS[0] + redS[1] + redS[2] + redS[3]);
    __syncthreads();
  }
  if (tid == 0) atomicAdd(acc, dtot);
}

// K6: apply label/margin, write scalar output
__global__ void kOut(const float* __restrict__ acc, const int* __restrict__ label,
                     float* __restrict__ out){
  if (threadIdx.x == 0 && blockIdx.x == 0){
    float d = *acc;
    out[0] = (*label) ? d : fmaxf(0.7f - d, 0.f);
  }
}

extern "C" void kernel_launch(void* const* d_in, const int* in_sizes, int n_in,
                              void* d_out, int out_size, void* d_ws, size_t ws_size,
                              hipStream_t stream){
  const float* x   = (const float*)d_in[0];
  const float* att = (const float*)d_in[1];
  const int* label = (const int*)d_in[2];
  float* W = (float*)d_ws;
  float* out = (float*)d_out;

  float* M = W;                                                   // 32 MB
  unsigned short* Mq  = (unsigned short*)(W + 8388608);           // 16 MB
  unsigned short* Mtq = (unsigned short*)(W + 8388608 + 4194304); // 16 MB
  float* S     = W + 16777216;
  float* qq    = S;
  float* tt    = qq + 1024;
  float* logmu = tt + 8192;
  float* lognu = logmu + 1024;
  float* u     = lognu + 8192;
  float* v     = u + 1024;
  float* acc   = v + 8192;
  float* prm   = acc + 1;           // [0]=min key, [1]=max key, [2]=mn, [3]=scale
  unsigned* prmI = (unsigned*)prm;
  int*   ctl   = (int*)(prm + 4);   // ctl[0..1] = "v changed" ping-pong flags

  hipLaunchKernelGGL(kPrep, dim3(37), dim3(256), 0, stream, x, att, qq, tt, logmu, lognu, u, v, acc, prmI, ctl);
  hipLaunchKernelGGL(kGemmM, dim3(128, 16), dim3(256), 0, stream, x, qq, tt, M, prmI);
  hipLaunchKernelGGL(kQuantTrans, dim3(128, 16), dim3(256), 0, stream, M, Mq, Mtq, prm);
  for (int it = 0; it < OT_ITERS; ++it){
    hipLaunchKernelGGL(kUPassQ, dim3(512), dim3(256), 0, stream, Mq, v, logmu, u, prm, ctl, it);
    hipLaunchKernelGGL(kVPassQ, dim3(512), dim3(256), 0, stream, Mtq, u, lognu, v, prm, ctl, it);
  }
  hipLaunchKernelGGL(kFinal, dim3(256), dim3(256), 0, stream, x, att, M, u, v, acc);
  hipLaunchKernelGGL(kOut, dim3(1), dim3(1), 0, stream, acc, label, out);
}

// Round 6
// 11878.740 us; speedup vs baseline: 1.0826x; 1.0826x over previous
//
#include <hip/hip_runtime.h>
#include <math.h>

// Problem constants (fixed by reference: x (9,256,32,32) fp32, att (9,32,32) fp32)
#define MR 1024      // m = 32*32 query locations
#define NC 8192      // n = 8*32*32 target locations
#define NCH 256      // channels
#define OT_ITERS 1000
#define IMG_STRIDE 262144  // 256*1024 floats per image
#define PBLK 512           // persistent grid: 2 blocks/CU

__device__ inline float wredMax(float v){
#pragma unroll
  for (int m = 32; m >= 1; m >>= 1) v = fmaxf(v, __shfl_xor(v, m, 64));
  return v;
}
__device__ inline float wredMin(float v){
#pragma unroll
  for (int m = 32; m >= 1; m >>= 1) v = fminf(v, __shfl_xor(v, m, 64));
  return v;
}
__device__ inline float wredSum(float v){
#pragma unroll
  for (int m = 32; m >= 1; m >>= 1) v += __shfl_xor(v, m, 64);
  return v;
}

// monotone float<->uint key (for atomicMin/Max over floats incl. negatives)
__device__ inline unsigned fkey(float f){
  unsigned b = __float_as_uint(f);
  return (b & 0x80000000u) ? ~b : (b | 0x80000000u);
}
__device__ inline float funkey(unsigned k){
  return (k & 0x80000000u) ? __uint_as_float(k & 0x7fffffffu) : __uint_as_float(~k);
}

// K1: squared norms, log marginals, zero-init u,v,acc, minmax keys, barrier state
__global__ __launch_bounds__(256) void kPrep(const float* __restrict__ x,
                                             const float* __restrict__ att,
                                             float* __restrict__ qq, float* __restrict__ tt,
                                             float* __restrict__ logmu, float* __restrict__ lognu,
                                             float* __restrict__ u, float* __restrict__ v,
                                             float* __restrict__ acc, unsigned* __restrict__ prmI,
                                             int* __restrict__ bar){
  int idx = blockIdx.x * 256 + threadIdx.x;
  if (idx < 9216){
    int img = idx >> 10, pos = idx & 1023;
    const float* p = x + img * IMG_STRIDE + pos;
    float s = 0.f;
#pragma unroll 8
    for (int c = 0; c < NCH; ++c){ float a = p[c * 1024]; s += a * a; }
    float lg = logf(att[idx]);
    if (img == 0){ qq[idx] = s;        logmu[idx] = lg; }
    else         { tt[idx - 1024] = s; lognu[idx - 1024] = lg; }
  }
  if (idx < MR) u[idx] = 0.f;
  if (idx < NC) v[idx] = 0.f;
  if (idx < 1024) bar[idx] = 0;
  if (idx == 0){ *acc = 0.f; prmI[0] = 0xFFFFFFFFu; prmI[1] = 0u; }
}

// K2: M[i][j] = qq[i] + tt[j] - 2 * Q_i . T_j ; also global min/max via key atomics
__global__ __launch_bounds__(256) void kGemmM(const float* __restrict__ x,
                                              const float* __restrict__ qq,
                                              const float* __restrict__ tt,
                                              float* __restrict__ M,
                                              unsigned* __restrict__ prmI){
  __shared__ float As[16][68];
  __shared__ float Bs[16][68];
  __shared__ float smn[4], smx[4];
  int jb = blockIdx.x;
  int ib = blockIdx.y;
  int i0 = ib * 64;
  int j0 = jb * 64;
  int k  = j0 >> 10, p0 = j0 & 1023;
  const float* A = x + i0;
  const float* B = x + (1 + k) * IMG_STRIDE + p0;
  int tid = threadIdx.x;
  int lr = tid >> 4, lc = (tid & 15) * 4;
  int ty = tid >> 4, tx = tid & 15;
  float accv[4][4] = {};
  for (int kt = 0; kt < 16; ++kt){
    int c = kt * 16 + lr;
    float4 av = *(const float4*)(A + c * 1024 + lc);
    float4 bv = *(const float4*)(B + c * 1024 + lc);
    *(float4*)(&As[lr][lc]) = av;
    *(float4*)(&Bs[lr][lc]) = bv;
    __syncthreads();
#pragma unroll
    for (int kk = 0; kk < 16; ++kk){
      float4 a = *(const float4*)(&As[kk][ty * 4]);
      float4 b = *(const float4*)(&Bs[kk][tx * 4]);
      float ar[4] = {a.x, a.y, a.z, a.w};
      float br[4] = {b.x, b.y, b.z, b.w};
#pragma unroll
      for (int r = 0; r < 4; ++r)
#pragma unroll
        for (int cc = 0; cc < 4; ++cc) accv[r][cc] += ar[r] * br[cc];
    }
    __syncthreads();
  }
  float tmn = INFINITY, tmx = -INFINITY;
#pragma unroll
  for (int r = 0; r < 4; ++r){
    int i = i0 + ty * 4 + r;
    float qi = qq[i];
    float o[4];
#pragma unroll
    for (int cc = 0; cc < 4; ++cc){
      o[cc] = qi + tt[j0 + tx * 4 + cc] - 2.f * accv[r][cc];
      tmn = fminf(tmn, o[cc]); tmx = fmaxf(tmx, o[cc]);
    }
    float4 ov = { o[0], o[1], o[2], o[3] };
    *(float4*)(M + (long)i * NC + j0 + tx * 4) = ov;
  }
  int lane = tid & 63, w = tid >> 6;
  tmn = wredMin(tmn); tmx = wredMax(tmx);
  if (lane == 0){ smn[w] = tmn; smx[w] = tmx; }
  __syncthreads();
  if (tid == 0){
    float bmn = fminf(fminf(smn[0], smn[1]), fminf(smn[2], smn[3]));
    float bmx = fmaxf(fmaxf(smx[0], smx[1]), fmaxf(smx[2], smx[3]));
    atomicMin(&prmI[0], fkey(bmn));
    atomicMax(&prmI[1], fkey(bmx));
  }
}

// K2b: one pass over M -> Mq (u16 row-major) + Mtq (u16 transposed); writes prm scale
__global__ __launch_bounds__(256) void kQuantTrans(const float* __restrict__ M,
                                                   unsigned short* __restrict__ Mq,
                                                   unsigned short* __restrict__ Mtq,
                                                   float* __restrict__ prm){
  __shared__ float tile[64][65];
  const unsigned* prmI = (const unsigned*)prm;
  float mn = funkey(prmI[0]);
  float mx = funkey(prmI[1]);
  float rng = mx - mn;
  float inv = (rng > 0.f) ? 65535.0f / rng : 0.f;
  float sc  = (rng > 0.f) ? rng / 65535.0f : 0.f;
  int i0 = blockIdx.y * 64;
  int j0 = blockIdx.x * 64;
  int t = threadIdx.x;
  int tc = t & 63, tr = t >> 6;
#pragma unroll
  for (int rr = 0; rr < 64; rr += 4)
    tile[rr + tr][tc] = M[(long)(i0 + rr + tr) * NC + j0 + tc];
  __syncthreads();
#pragma unroll
  for (int rr = 0; rr < 64; rr += 4){
    float a = tile[rr + tr][tc];
    int qa = (int)lrintf((a - mn) * inv);
    qa = qa < 0 ? 0 : (qa > 65535 ? 65535 : qa);
    Mq[(long)(i0 + rr + tr) * NC + j0 + tc] = (unsigned short)qa;
    float b = tile[tc][rr + tr];
    int qb = (int)lrintf((b - mn) * inv);
    qb = qb < 0 ? 0 : (qb > 65535 ? 65535 : qb);
    Mtq[(long)(j0 + rr + tr) * MR + i0 + tc] = (unsigned short)qb;
  }
  if (blockIdx.x == 0 && blockIdx.y == 0 && t == 0){ prm[2] = mn; prm[3] = sc; }
}

// hierarchical epoch grid barrier: 8 groups of 64 blocks; relaxed atomics only
// (no acquire fences -> no L2 invalidate -> Mq/Mtq stay L2-resident)
__device__ inline void gbar(int* bar, int g, int ep){
  __syncthreads();
  if (threadIdx.x == 0){
    asm volatile("s_waitcnt vmcnt(0)" ::: "memory");  // prior agent-stores complete
    int a = __hip_atomic_fetch_add(&bar[g * 32], 1, __ATOMIC_RELAXED, __HIP_MEMORY_SCOPE_AGENT);
    if (a == 64 * ep - 1){                            // last arrival of this group
      int go = __hip_atomic_fetch_add(&bar[512], 1, __ATOMIC_RELAXED, __HIP_MEMORY_SCOPE_AGENT);
      if (go == 8 * ep - 1){                          // last group: publish release epoch
#pragma unroll
        for (int g2 = 0; g2 < 8; ++g2)
          __hip_atomic_store(&bar[256 + g2 * 32], ep, __ATOMIC_RELAXED, __HIP_MEMORY_SCOPE_AGENT);
      }
    }
    while (__hip_atomic_load(&bar[256 + g * 32], __ATOMIC_RELAXED, __HIP_MEMORY_SCOPE_AGENT) < ep)
      __builtin_amdgcn_s_sleep(4);
  }
  __syncthreads();
}

// persistent Sinkhorn: 512 blocks; each owns 2 u-rows (Mq) + 16 v-cols (Mtq).
// u/v exchanged via agent-scope atomics (coherent, cache-bypassing); Mq/Mtq via
// normal loads (immutable -> local L2 residency across all iterations).
__global__ __launch_bounds__(256, 2) void kSink2(const unsigned short* __restrict__ Mq,
                                                 const unsigned short* __restrict__ Mtq,
                                                 const float* __restrict__ logmu,
                                                 const float* __restrict__ lognu,
                                                 float* __restrict__ u,
                                                 float* __restrict__ v,
                                                 const float* __restrict__ prm,
                                                 int* __restrict__ bar){
  __shared__ float sh[8192];
  __shared__ float redA0[4], redA1[4], redB0[4], redB1[4];
  int tid = threadIdx.x, b = blockIdx.x;
  int lane = tid & 63, w = tid >> 6;
  int g = b & 7;
  float mn = prm[2], s = prm[3];
  int r0 = 2 * b;
  const unsigned short* R0 = Mq + (long)r0 * NC;
  const unsigned short* R1 = R0 + NC;
  float lmu0 = logmu[r0], lmu1 = logmu[r0 + 1];
  float lnu[4];
#pragma unroll
  for (int cc = 0; cc < 4; ++cc) lnu[cc] = lognu[16 * b + w * 4 + cc];
  int ep = 0;

  for (int it = 0; it < OT_ITERS; ++it){
    // ---- stage v into LDS (coalesced agent-scope loads, batched) ----
#pragma unroll
    for (int h = 0; h < 2; ++h){
      float tmp[16];
#pragma unroll
      for (int q = 0; q < 16; ++q)
        tmp[q] = __hip_atomic_load(v + (h * 16 + q) * 256 + tid, __ATOMIC_RELAXED, __HIP_MEMORY_SCOPE_AGENT);
#pragma unroll
      for (int q = 0; q < 16; ++q)
        sh[(h * 16 + q) * 256 + tid] = tmp[q];
    }
    __syncthreads();
    // ---- u-pass: rows r0, r0+1 (R4-proven math, v from LDS) ----
    float t0[32], t1[32];
    float mx0 = -INFINITY, mx1 = -INFINITY;
#pragma unroll
    for (int kb = 0; kb < 4; ++kb){
      int cidx = kb * 2048 + tid * 8;
      uint4 qa = *(const uint4*)(R0 + cidx);
      uint4 qb = *(const uint4*)(R1 + cidx);
      float4 v0 = *(const float4*)(&sh[cidx]);
      float4 v1 = *(const float4*)(&sh[cidx + 4]);
      float a0 = fmaf(s, (float)(qa.x & 0xFFFFu), v0.x);
      float a1 = fmaf(s, (float)(qa.x >> 16),     v0.y);
      float a2 = fmaf(s, (float)(qa.y & 0xFFFFu), v0.z);
      float a3 = fmaf(s, (float)(qa.y >> 16),     v0.w);
      float a4 = fmaf(s, (float)(qa.z & 0xFFFFu), v1.x);
      float a5 = fmaf(s, (float)(qa.z >> 16),     v1.y);
      float a6 = fmaf(s, (float)(qa.w & 0xFFFFu), v1.z);
      float a7 = fmaf(s, (float)(qa.w >> 16),     v1.w);
      float c0 = fmaf(s, (float)(qb.x & 0xFFFFu), v0.x);
      float c1 = fmaf(s, (float)(qb.x >> 16),     v0.y);
      float c2 = fmaf(s, (float)(qb.y & 0xFFFFu), v0.z);
      float c3 = fmaf(s, (float)(qb.y >> 16),     v0.w);
      float c4 = fmaf(s, (float)(qb.z & 0xFFFFu), v1.x);
      float c5 = fmaf(s, (float)(qb.z >> 16),     v1.y);
      float c6 = fmaf(s, (float)(qb.w & 0xFFFFu), v1.z);
      float c7 = fmaf(s, (float)(qb.w >> 16),     v1.w);
      t0[kb*8+0]=a0; t0[kb*8+1]=a1; t0[kb*8+2]=a2; t0[kb*8+3]=a3;
      t0[kb*8+4]=a4; t0[kb*8+5]=a5; t0[kb*8+6]=a6; t0[kb*8+7]=a7;
      t1[kb*8+0]=c0; t1[kb*8+1]=c1; t1[kb*8+2]=c2; t1[kb*8+3]=c3;
      t1[kb*8+4]=c4; t1[kb*8+5]=c5; t1[kb*8+6]=c6; t1[kb*8+7]=c7;
      mx0 = fmaxf(mx0, fmaxf(fmaxf(fmaxf(a0,a1),fmaxf(a2,a3)), fmaxf(fmaxf(a4,a5),fmaxf(a6,a7))));
      mx1 = fmaxf(mx1, fmaxf(fmaxf(fmaxf(c0,c1),fmaxf(c2,c3)), fmaxf(fmaxf(c4,c5),fmaxf(c6,c7))));
    }
    float wm0 = wredMax(mx0), wm1 = wredMax(mx1);
    if (lane == 0){ redA0[w] = wm0; redA1[w] = wm1; }
    __syncthreads();
    float bm0 = fmaxf(fmaxf(redA0[0], redA0[1]), fmaxf(redA0[2], redA0[3]));
    float bm1 = fmaxf(fmaxf(redA1[0], redA1[1]), fmaxf(redA1[2], redA1[3]));
    float s0 = 0.f, s1 = 0.f;
#pragma unroll
    for (int q = 0; q < 32; ++q){ s0 += __expf(t0[q] - bm0); s1 += __expf(t1[q] - bm1); }
    s0 = wredSum(s0); s1 = wredSum(s1);
    if (lane == 0){ redB0[w] = s0; redB1[w] = s1; }
    __syncthreads();
    if (tid == 0){
      float nu0 = lmu0 - mn - (bm0 + __logf(redB0[0] + redB0[1] + redB0[2] + redB0[3]));
      float nu1 = lmu1 - mn - (bm1 + __logf(redB1[0] + redB1[1] + redB1[2] + redB1[3]));
      __hip_atomic_store(u + r0,     nu0, __ATOMIC_RELAXED, __HIP_MEMORY_SCOPE_AGENT);
      __hip_atomic_store(u + r0 + 1, nu1, __ATOMIC_RELAXED, __HIP_MEMORY_SCOPE_AGENT);
    }
    gbar(bar, g, ++ep);   // u complete everywhere

    // ---- stage u into LDS ----
    {
      float tu[4];
#pragma unroll
      for (int q = 0; q < 4; ++q)
        tu[q] = __hip_atomic_load(u + q * 256 + tid, __ATOMIC_RELAXED, __HIP_MEMORY_SCOPE_AGENT);
#pragma unroll
      for (int q = 0; q < 4; ++q) sh[q * 256 + tid] = tu[q];
    }
    __syncthreads();
    // ---- v-pass: 16 cols per block (R4-proven math, u from LDS) ----
#pragma unroll
    for (int cc = 0; cc < 4; ++cc){
      int j = 16 * b + w * 4 + cc;
      const unsigned short* R = Mtq + (long)j * MR;
      uint4 qa = *(const uint4*)(R + lane * 8);
      uint4 qb = *(const uint4*)(R + 512 + lane * 8);
      float4 ua0 = *(const float4*)(&sh[lane * 8]);
      float4 ua1 = *(const float4*)(&sh[lane * 8 + 4]);
      float4 ub0 = *(const float4*)(&sh[512 + lane * 8]);
      float4 ub1 = *(const float4*)(&sh[512 + lane * 8 + 4]);
      float tv[16];
      tv[0]  = fmaf(s, (float)(qa.x & 0xFFFFu), ua0.x);
      tv[1]  = fmaf(s, (float)(qa.x >> 16),     ua0.y);
      tv[2]  = fmaf(s, (float)(qa.y & 0xFFFFu), ua0.z);
      tv[3]  = fmaf(s, (float)(qa.y >> 16),     ua0.w);
      tv[4]  = fmaf(s, (float)(qa.z & 0xFFFFu), ua1.x);
      tv[5]  = fmaf(s, (float)(qa.z >> 16),     ua1.y);
      tv[6]  = fmaf(s, (float)(qa.w & 0xFFFFu), ua1.z);
      tv[7]  = fmaf(s, (float)(qa.w >> 16),     ua1.w);
      tv[8]  = fmaf(s, (float)(qb.x & 0xFFFFu), ub0.x);
      tv[9]  = fmaf(s, (float)(qb.x >> 16),     ub0.y);
      tv[10] = fmaf(s, (float)(qb.y & 0xFFFFu), ub0.z);
      tv[11] = fmaf(s, (float)(qb.y >> 16),     ub0.w);
      tv[12] = fmaf(s, (float)(qb.z & 0xFFFFu), ub1.x);
      tv[13] = fmaf(s, (float)(qb.z >> 16),     ub1.y);
      tv[14] = fmaf(s, (float)(qb.w & 0xFFFFu), ub1.z);
      tv[15] = fmaf(s, (float)(qb.w >> 16),     ub1.w);
      float mx = -INFINITY;
#pragma unroll
      for (int q = 0; q < 16; ++q) mx = fmaxf(mx, tv[q]);
      mx = wredMax(mx);
      float sm = 0.f;
#pragma unroll
      for (int q = 0; q < 16; ++q) sm += __expf(tv[q] - mx);
      sm = wredSum(sm);
      if (lane == 0)
        __hip_atomic_store(v + j, lnu[cc] - mn - (mx + __logf(sm)),
                           __ATOMIC_RELAXED, __HIP_MEMORY_SCOPE_AGENT);
    }
    gbar(bar, g, ++ep);   // v complete everywhere
  }
}

// fallback (R4 path, no early-exit): used only if cooperative launch fails
__global__ __launch_bounds__(256) void kUPassQ(const unsigned short* __restrict__ Mq,
                                               const float* __restrict__ v,
                                               const float* __restrict__ logmu,
                                               float* __restrict__ u,
                                               const float* __restrict__ prm){
  int b = blockIdx.x, tid = threadIdx.x;
  float mn = prm[2], s = prm[3];
  int r0 = 2 * b;
  const unsigned short* R0 = Mq + (long)r0 * NC;
  const unsigned short* R1 = R0 + NC;
  float t0[32], t1[32];
  float mx0 = -INFINITY, mx1 = -INFINITY;
#pragma unroll
  for (int kb = 0; kb < 4; ++kb){
    int cidx = kb * 2048 + tid * 8;
    uint4 qa = *(const uint4*)(R0 + cidx);
    uint4 qb = *(const uint4*)(R1 + cidx);
    float4 v0 = *(const float4*)(v + cidx);
    float4 v1 = *(const float4*)(v + cidx + 4);
    float a0 = fmaf(s, (float)(qa.x & 0xFFFFu), v0.x);
    float a1 = fmaf(s, (float)(qa.x >> 16),     v0.y);
    float a2 = fmaf(s, (float)(qa.y & 0xFFFFu), v0.z);
    float a3 = fmaf(s, (float)(qa.y >> 16),     v0.w);
    float a4 = fmaf(s, (float)(qa.z & 0xFFFFu), v1.x);
    float a5 = fmaf(s, (float)(qa.z >> 16),     v1.y);
    float a6 = fmaf(s, (float)(qa.w & 0xFFFFu), v1.z);
    float a7 = fmaf(s, (float)(qa.w >> 16),     v1.w);
    float c0 = fmaf(s, (float)(qb.x & 0xFFFFu), v0.x);
    float c1 = fmaf(s, (float)(qb.x >> 16),     v0.y);
    float c2 = fmaf(s, (float)(qb.y & 0xFFFFu), v0.z);
    float c3 = fmaf(s, (float)(qb.y >> 16),     v0.w);
    float c4 = fmaf(s, (float)(qb.z & 0xFFFFu), v1.x);
    float c5 = fmaf(s, (float)(qb.z >> 16),     v1.y);
    float c6 = fmaf(s, (float)(qb.w & 0xFFFFu), v1.z);
    float c7 = fmaf(s, (float)(qb.w >> 16),     v1.w);
    t0[kb*8+0]=a0; t0[kb*8+1]=a1; t0[kb*8+2]=a2; t0[kb*8+3]=a3;
    t0[kb*8+4]=a4; t0[kb*8+5]=a5; t0[kb*8+6]=a6; t0[kb*8+7]=a7;
    t1[kb*8+0]=c0; t1[kb*8+1]=c1; t1[kb*8+2]=c2; t1[kb*8+3]=c3;
    t1[kb*8+4]=c4; t1[kb*8+5]=c5; t1[kb*8+6]=c6; t1[kb*8+7]=c7;
    mx0 = fmaxf(mx0, fmaxf(fmaxf(fmaxf(a0,a1),fmaxf(a2,a3)), fmaxf(fmaxf(a4,a5),fmaxf(a6,a7))));
    mx1 = fmaxf(mx1, fmaxf(fmaxf(fmaxf(c0,c1),fmaxf(c2,c3)), fmaxf(fmaxf(c4,c5),fmaxf(c6,c7))));
  }
  __shared__ float redA0[4], redA1[4], redB0[4], redB1[4];
  int lane = tid & 63, w = tid >> 6;
  float wm0 = wredMax(mx0), wm1 = wredMax(mx1);
  if (lane == 0){ redA0[w] = wm0; redA1[w] = wm1; }
  __syncthreads();
  float bm0 = fmaxf(fmaxf(redA0[0], redA0[1]), fmaxf(redA0[2], redA0[3]));
  float bm1 = fmaxf(fmaxf(redA1[0], redA1[1]), fmaxf(redA1[2], redA1[3]));
  float s0 = 0.f, s1 = 0.f;
#pragma unroll
  for (int q = 0; q < 32; ++q){ s0 += __expf(t0[q] - bm0); s1 += __expf(t1[q] - bm1); }
  s0 = wredSum(s0); s1 = wredSum(s1);
  if (lane == 0){ redB0[w] = s0; redB1[w] = s1; }
  __syncthreads();
  if (tid == 0){
    u[r0]     = logmu[r0]     - mn - (bm0 + __logf(redB0[0] + redB0[1] + redB0[2] + redB0[3]));
    u[r0 + 1] = logmu[r0 + 1] - mn - (bm1 + __logf(redB1[0] + redB1[1] + redB1[2] + redB1[3]));
  }
}

__global__ __launch_bounds__(256) void kVPassQ(const unsigned short* __restrict__ Mtq,
                                               const float* __restrict__ u,
                                               const float* __restrict__ lognu,
                                               float* __restrict__ v,
                                               const float* __restrict__ prm){
  __shared__ float ulds[1024];
  int tid = threadIdx.x;
  float mn = prm[2], s = prm[3];
  *(float4*)(&ulds[tid * 4]) = *(const float4*)(u + tid * 4);
  __syncthreads();
  int w = tid >> 6, lane = tid & 63;
#pragma unroll
  for (int cc = 0; cc < 4; ++cc){
    int j = blockIdx.x * 16 + w * 4 + cc;
    const unsigned short* R = Mtq + (long)j * MR;
    uint4 qa = *(const uint4*)(R + lane * 8);
    uint4 qb = *(const uint4*)(R + 512 + lane * 8);
    float4 ua0 = *(const float4*)(&ulds[lane * 8]);
    float4 ua1 = *(const float4*)(&ulds[lane * 8 + 4]);
    float4 ub0 = *(const float4*)(&ulds[512 + lane * 8]);
    float4 ub1 = *(const float4*)(&ulds[512 + lane * 8 + 4]);
    float tv[16];
    tv[0]  = fmaf(s, (float)(qa.x & 0xFFFFu), ua0.x);
    tv[1]  = fmaf(s, (float)(qa.x >> 16),     ua0.y);
    tv[2]  = fmaf(s, (float)(qa.y & 0xFFFFu), ua0.z);
    tv[3]  = fmaf(s, (float)(qa.y >> 16),     ua0.w);
    tv[4]  = fmaf(s, (float)(qa.z & 0xFFFFu), ua1.x);
    tv[5]  = fmaf(s, (float)(qa.z >> 16),     ua1.y);
    tv[6]  = fmaf(s, (float)(qa.w & 0xFFFFu), ua1.z);
    tv[7]  = fmaf(s, (float)(qa.w >> 16),     ua1.w);
    tv[8]  = fmaf(s, (float)(qb.x & 0xFFFFu), ub0.x);
    tv[9]  = fmaf(s, (float)(qb.x >> 16),     ub0.y);
    tv[10] = fmaf(s, (float)(qb.y & 0xFFFFu), ub0.z);
    tv[11] = fmaf(s, (float)(qb.y >> 16),     ub0.w);
    tv[12] = fmaf(s, (float)(qb.z & 0xFFFFu), ub1.x);
    tv[13] = fmaf(s, (float)(qb.z >> 16),     ub1.y);
    tv[14] = fmaf(s, (float)(qb.w & 0xFFFFu), ub1.z);
    tv[15] = fmaf(s, (float)(qb.w >> 16),     ub1.w);
    float mx = -INFINITY;
#pragma unroll
    for (int q = 0; q < 16; ++q) mx = fmaxf(mx, tv[q]);
    mx = wredMax(mx);
    float sm = 0.f;
#pragma unroll
    for (int q = 0; q < 16; ++q) sm += __expf(tv[q] - mx);
    sm = wredSum(sm);
    if (lane == 0) v[j] = lognu[j] - mn - (mx + __logf(sm));
  }
}

// K5: o = P@T rows, diff = mu*Q - o, acc += sum_i ||diff_i||_2 ; 4 rows per block
__global__ __launch_bounds__(256) void kFinal(const float* __restrict__ x,
                                              const float* __restrict__ att,
                                              const float* __restrict__ M,
                                              const float* __restrict__ u,
                                              const float* __restrict__ v,
                                              float* __restrict__ acc){
  __shared__ float pch[4][256];
  __shared__ float redS[4];
  int tid = threadIdx.x;
  int r0 = blockIdx.x * 4;
  float u4[4];
#pragma unroll
  for (int rr = 0; rr < 4; ++rr) u4[rr] = u[r0 + rr];
  float o[4] = {0.f, 0.f, 0.f, 0.f};
  for (int jc = 0; jc < NC; jc += 256){
    float vv = v[jc + tid];
#pragma unroll
    for (int rr = 0; rr < 4; ++rr)
      pch[rr][tid] = __expf(M[(long)(r0 + rr) * NC + jc + tid] + u4[rr] + vv);
    __syncthreads();
    int k = jc >> 10;
    const float* Tp = x + (1 + k) * IMG_STRIDE + tid * 1024 + (jc & 1023);
    for (int jj = 0; jj < 256; jj += 4){
      float4 tv = *(const float4*)(Tp + jj);
      float tq[4] = {tv.x, tv.y, tv.z, tv.w};
#pragma unroll
      for (int q = 0; q < 4; ++q){
        o[0] += pch[0][jj + q] * tq[q];
        o[1] += pch[1][jj + q] * tq[q];
        o[2] += pch[2][jj + q] * tq[q];
        o[3] += pch[3][jj + q] * tq[q];
      }
    }
    __syncthreads();
  }
  int lane = tid & 63, wid = tid >> 6;
  float dtot = 0.f;
#pragma unroll
  for (int rr = 0; rr < 4; ++rr){
    float mu = att[r0 + rr];
    float qv = x[tid * 1024 + (r0 + rr)];
    float diff = mu * qv - o[rr];
    float wsum = wredSum(diff * diff);
    if (lane == 0) redS[wid] = wsum;
    __syncthreads();
    if (tid == 0) dtot += sqrtf(redS[0] + redS[1] + redS[2] + redS[3]);
    __syncthreads();
  }
  if (tid == 0) atomicAdd(acc, dtot);
}

// K6: apply label/margin, write scalar output
__global__ void kOut(const float* __restrict__ acc, const int* __restrict__ label,
                     float* __restrict__ out){
  if (threadIdx.x == 0 && blockIdx.x == 0){
    float d = *acc;
    out[0] = (*label) ? d : fmaxf(0.7f - d, 0.f);
  }
}

extern "C" void kernel_launch(void* const* d_in, const int* in_sizes, int n_in,
                              void* d_out, int out_size, void* d_ws, size_t ws_size,
                              hipStream_t stream){
  const float* x   = (const float*)d_in[0];
  const float* att = (const float*)d_in[1];
  const int* label = (const int*)d_in[2];
  float* W = (float*)d_ws;
  float* out = (float*)d_out;

  float* M = W;                                                   // 32 MB
  unsigned short* Mq  = (unsigned short*)(W + 8388608);           // 16 MB
  unsigned short* Mtq = (unsigned short*)(W + 8388608 + 4194304); // 16 MB
  float* S     = W + 16777216;
  float* qq    = S;
  float* tt    = qq + 1024;
  float* logmu = tt + 8192;
  float* lognu = logmu + 1024;
  float* u     = lognu + 8192;
  float* v     = u + 1024;
  float* acc   = v + 8192;
  float* prm   = acc + 1;           // [0]=min key, [1]=max key, [2]=mn, [3]=scale
  unsigned* prmI = (unsigned*)prm;
  int*   bar   = (int*)(prm + 4);   // 1024 ints barrier state

  hipLaunchKernelGGL(kPrep, dim3(37), dim3(256), 0, stream, x, att, qq, tt, logmu, lognu, u, v, acc, prmI, bar);
  hipLaunchKernelGGL(kGemmM, dim3(128, 16), dim3(256), 0, stream, x, qq, tt, M, prmI);
  hipLaunchKernelGGL(kQuantTrans, dim3(128, 16), dim3(256), 0, stream, M, Mq, Mtq, prm);

  void* args[] = { (void*)&Mq, (void*)&Mtq, (void*)&logmu, (void*)&lognu,
                   (void*)&u, (void*)&v, (void*)&prm, (void*)&bar };
  hipError_t rc = hipLaunchCooperativeKernel((const void*)kSink2,
                                             dim3(PBLK), dim3(256), args, 0, stream);
  if (rc != hipSuccess){
    for (int it = 0; it < OT_ITERS; ++it){
      hipLaunchKernelGGL(kUPassQ, dim3(512), dim3(256), 0, stream, Mq, v, logmu, u, prm);
      hipLaunchKernelGGL(kVPassQ, dim3(512), dim3(256), 0, stream, Mtq, u, lognu, v, prm);
    }
  }
  hipLaunchKernelGGL(kFinal, dim3(256), dim3(256), 0, stream, x, att, M, u, v, acc);
  hipLaunchKernelGGL(kOut, dim3(1), dim3(1), 0, stream, acc, label, out);
}